// Round 3
// baseline (3645.273 us; speedup 1.0000x reference)
//
#include <hip/hip_runtime.h>
#include <hip/hip_bf16.h>
#include <math.h>

// Problem constants
#define Bb   128
#define Ss   64
#define Tt   50
#define Ff   100
#define DAa  350
#define Rr   30
#define HFCc 100
#define Hh   100
#define PITCH 352   // row pitch (floats) for xW chunk and WT (350 padded to 352)
#define UP    356   // padded d-length (356 = 4*89 quads), zero-padded 350..355

// ws layout (float indices), all 16B-aligned:
#define WS_WT    0        // 100 x 352            = 35200
#define WS_UPAD  35200    // 30 x 356             = 10680
#define WS_WCT   45880    // 100 x 356            = 35600
#define WS_BPAD  81480    // 356 (+ pad to 81840)
#define WS_HST   81840    // 128 x 100            = 12800
#define WS_XW    94640    // SC * 128 * 50 * 352

// ---------------------------------------------------------------------------
// Prep: WT[k][col]=W[col][k] (100x352); u_pad[r][d] (30x356, zero pad);
// WcT[k][d]=Wc[d][k] (100x356, zero pad); b_pad[d] (356, zero pad).
// ---------------------------------------------------------------------------
__global__ __launch_bounds__(256) void k_prep(const float* __restrict__ W,
                                              const float* __restrict__ u,
                                              const float* __restrict__ Wc,
                                              const float* __restrict__ bvec,
                                              float* __restrict__ ws) {
  int i = blockIdx.x * 256 + threadIdx.x;
  if (i < 100 * PITCH) {
    int k = i / PITCH, col = i % PITCH;
    ws[WS_WT + i] = (col < DAa) ? W[col * Ff + k] : 0.0f;
  }
  if (i < Rr * UP) {
    int r = i / UP, d = i % UP;
    ws[WS_UPAD + i] = (d < DAa) ? u[r * DAa + d] : 0.0f;
  }
  if (i < Hh * UP) {
    int k = i / UP, d = i % UP;
    ws[WS_WCT + i] = (d < DAa) ? Wc[d * Hh + k] : 0.0f;
  }
  if (i < UP) {
    ws[WS_BPAD + i] = (i < DAa) ? bvec[i] : 0.0f;
  }
}

// ---------------------------------------------------------------------------
// xW chunk GEMM: rows rch = ((b*SC + sl)*50 + t), cols = DA (pitch 352).
// C[rch][col] = sum_k x[b, c*SC+sl, t, k] * W[col][k].  BM=64, BN=128, K=100.
// grid = (100*SC, 3), block = 256.  Pad cols 350/351 get 0 (WT zero-padded).
// ---------------------------------------------------------------------------
__global__ __launch_bounds__(256) void k_gemm(const float* __restrict__ x,
                                              const float* __restrict__ WT,
                                              float* __restrict__ xw,
                                              int c, int SC) {
  __shared__ __align__(16) float As[64][108];   // [m][k]
  __shared__ __align__(16) float Bs[100][128];  // [k][col]
  const int tid = threadIdx.x;
  const int mt = blockIdx.x;
  const int nt = blockIdx.y;
  const int rowsPerB = SC * Tt;

  for (int i = tid; i < 1600; i += 256) {
    int m = i / 25, k4 = (i % 25) * 4;
    int rch = mt * 64 + m;
    int b = rch / rowsPerB, rem = rch % rowsPerB;
    int sl = rem / Tt, t = rem % Tt;
    const float4 v = *(const float4*)&x[((size_t)((b * Ss + c * SC + sl) * Tt) + t) * Ff + k4];
    *(float4*)&As[m][k4] = v;
  }
  for (int i = tid; i < 3200; i += 256) {
    int k = i / 32, j4 = (i % 32) * 4;
    int col4 = nt * 128 + j4;
    float4 v = make_float4(0.f, 0.f, 0.f, 0.f);
    if (col4 < PITCH) v = *(const float4*)&WT[k * PITCH + col4];
    *(float4*)&Bs[k][j4] = v;
  }
  __syncthreads();

  const int tx = tid % 16, ty = tid / 16;
  float acc[4][8];
#pragma unroll
  for (int i = 0; i < 4; ++i)
#pragma unroll
    for (int j = 0; j < 8; ++j) acc[i][j] = 0.f;

#pragma unroll 4
  for (int k = 0; k < 100; ++k) {
    float a[4];
#pragma unroll
    for (int i = 0; i < 4; ++i) a[i] = As[ty * 4 + i][k];
    float4 b0 = *(float4*)&Bs[k][tx * 8];
    float4 b1 = *(float4*)&Bs[k][tx * 8 + 4];
#pragma unroll
    for (int i = 0; i < 4; ++i) {
      acc[i][0] += a[i] * b0.x; acc[i][1] += a[i] * b0.y;
      acc[i][2] += a[i] * b0.z; acc[i][3] += a[i] * b0.w;
      acc[i][4] += a[i] * b1.x; acc[i][5] += a[i] * b1.y;
      acc[i][6] += a[i] * b1.z; acc[i][7] += a[i] * b1.w;
    }
  }

  const int col4 = nt * 128 + tx * 8;
#pragma unroll
  for (int i = 0; i < 4; ++i) {
    int rch = mt * 64 + ty * 4 + i;
    float* dst = &xw[(size_t)rch * PITCH + col4];
    if (col4 <= 348)
      *(float4*)dst = make_float4(acc[i][0], acc[i][1], acc[i][2], acc[i][3]);
    if (col4 + 4 <= 348)
      *(float4*)(dst + 4) = make_float4(acc[i][4], acc[i][5], acc[i][6], acc[i][7]);
  }
}

// ---------------------------------------------------------------------------
// Persistent per-b scan over SC sentences. grid = 128, block = 512 (8 waves).
// LDS scratch (51.2 KB) is overlaid: ctx partials / ait wave-partials /
// fc partials / GRU partials / hp partials — phases disjoint, barrier-split.
// ---------------------------------------------------------------------------
__global__ __launch_bounds__(512) void k_scan(
    const float* __restrict__ x, const float* __restrict__ xw,
    const float* __restrict__ WcT, const float* __restrict__ b_pad,
    const float* __restrict__ u_pad, const float* __restrict__ Wfc,
    const float* __restrict__ bfc,
    const float* __restrict__ Wz, const float* __restrict__ Wr,
    const float* __restrict__ Wh, const float* __restrict__ Uz,
    const float* __restrict__ Ur, const float* __restrict__ Uh,
    const float* __restrict__ bz, const float* __restrict__ br,
    const float* __restrict__ bh,
    float* __restrict__ out, float* __restrict__ hstate, int c, int SC) {
  __shared__ __align__(16) float uit_s[Tt][UP];   // 71.2 KB
  __shared__ __align__(16) float scratch[12800];  // 51.2 KB overlay
  __shared__ __align__(16) float ait_s[Rr * Tt];  // 6 KB; [t*30+r] == reshaped [r*50+t]
  __shared__ __align__(16) float M_s[Rr][104];    // 12.5 KB
  __shared__ __align__(16) float ctx_s[UP];
  __shared__ __align__(16) float h_sm[Hh];
  __shared__ __align__(16) float fc_sm[HFCc];
  __shared__ float z_sm[Hh], r_sm[Hh], rh_sm[Hh], hc1_sm[Hh];

  const int tid = threadIdx.x;
  const int b = blockIdx.x;
  const int lane = tid & 63;
  const int w = tid >> 6;
  // wave-uniform d-segment bounds (quads of 4 floats, 89 total): 7x11 + 1x12
  const int wu = __builtin_amdgcn_readfirstlane(w);
  const int q0 = wu * 11;
  const int q1 = (wu == 7) ? 89 : q0 + 11;
  const int tl = (lane < Tt) ? lane : (Tt - 1);  // lanes 50..63 redundant

  // one-time init: zero uit cols 352..355 (never written per-step), carry h
  if (tid < Tt * 4) uit_s[tid >> 2][352 + (tid & 3)] = 0.f;
  if (tid < Hh) h_sm[tid] = (c == 0) ? 0.f : hstate[b * Hh + tid];
  __syncthreads();

  for (int sl = 0; sl < SC; ++sl) {
    const int sg = c * SC + sl;

    // ---- ctx partials: 356 threads = (ks in [0,4)) x (dq in [0,89))
    if (tid < 356) {
      const int ks = tid / 89, dq = tid % 89;
      float4 a = make_float4(0.f, 0.f, 0.f, 0.f);
      const float* wp = &WcT[ks * 25 * UP + dq * 4];
#pragma unroll 5
      for (int k = 0; k < 25; ++k) {
        const float hk = h_sm[ks * 25 + k];
        const float4 wv = *(const float4*)&wp[k * UP];
        a.x = fmaf(wv.x, hk, a.x); a.y = fmaf(wv.y, hk, a.y);
        a.z = fmaf(wv.z, hk, a.z); a.w = fmaf(wv.w, hk, a.w);
      }
      *(float4*)&scratch[ks * UP + dq * 4] = a;
    }
    __syncthreads();
    if (tid < 356)
      ctx_s[tid] = b_pad[tid] + scratch[tid] + scratch[UP + tid] +
                   scratch[2 * UP + tid] + scratch[3 * UP + tid];
    __syncthreads();

    // ---- uit[t][q*4..] = tanh(xw + ctx), float4 (88 quads/row; pads are 0)
    {
      const size_t rbase = (size_t)(b * SC + sl) * Tt;
      for (int e = tid; e < Tt * 88; e += 512) {
        int t = e / 88, q = e % 88;
        float4 v = *(const float4*)&xw[(rbase + t) * PITCH + q * 4];
        const float4 cv = *(const float4*)&ctx_s[q * 4];
        v.x = tanhf(v.x + cv.x); v.y = tanhf(v.y + cv.y);
        v.z = tanhf(v.z + cv.z); v.w = tanhf(v.w + cv.w);
        *(float4*)&uit_s[t][q * 4] = v;
      }
    }
    __syncthreads();

    // ---- ait partials: lane=t, wave=d-segment; u via wave-uniform loads
    {
      float pacc[Rr];
#pragma unroll
      for (int r = 0; r < Rr; ++r) pacc[r] = 0.f;
      for (int q = q0; q < q1; ++q) {
        const float4 tv = *(const float4*)&uit_s[tl][q * 4];
#pragma unroll
        for (int r = 0; r < Rr; ++r) {
          const float4 uv = *(const float4*)&u_pad[r * UP + q * 4];  // uniform
          pacc[r] = fmaf(tv.x, uv.x,
                     fmaf(tv.y, uv.y,
                      fmaf(tv.z, uv.z,
                       fmaf(tv.w, uv.w, pacc[r]))));
        }
      }
      if (lane < Tt) {
        float* pb = &scratch[w * 1600 + lane * 32];  // stride-32 padded
#pragma unroll
        for (int r4 = 0; r4 < 28; r4 += 4)
          *(float4*)&pb[r4] = make_float4(pacc[r4], pacc[r4 + 1], pacc[r4 + 2], pacc[r4 + 3]);
        pb[28] = pacc[28]; pb[29] = pacc[29];
      }
    }
    __syncthreads();

    // ---- reduce 8 wave-partials -> ait_s[t*30+r]
    for (int o = tid; o < Tt * Rr; o += 512) {
      const int t = o / Rr, r = o % Rr;
      float s = 0.f;
#pragma unroll
      for (int ww = 0; ww < 8; ++ww) s += scratch[ww * 1600 + t * 32 + r];
      ait_s[o] = s;
    }
    __syncthreads();

    // ---- softmax over reinterpreted rows: row rr = ait_s[rr*50 .. rr*50+49]
    if (tid < 240) {
      int rr = tid / 8, l = tid % 8;
      float m = -1e30f;
      for (int t = l; t < Tt; t += 8) m = fmaxf(m, ait_s[rr * Tt + t]);
#pragma unroll
      for (int o = 4; o >= 1; o >>= 1) m = fmaxf(m, __shfl_xor(m, o, 8));
      float ssum = 0.f;
      for (int t = l; t < Tt; t += 8) ssum += expf(ait_s[rr * Tt + t] - m);
#pragma unroll
      for (int o = 4; o >= 1; o >>= 1) ssum += __shfl_xor(ssum, o, 8);
      float inv = 1.0f / ssum;
      for (int t = l; t < Tt; t += 8)
        ait_s[rr * Tt + t] = expf(ait_s[rr * Tt + t] - m) * inv;
    }
    __syncthreads();

    // ---- M[r][f] = sum_t A[r][t] * x[b,sg,t,f]
    if (tid < 500) {
      int f = tid % 100, q = tid / 100, r0 = q * 6;
      float acc[6] = {0.f, 0.f, 0.f, 0.f, 0.f, 0.f};
      const float* xp = &x[((size_t)(b * Ss + sg) * Tt) * Ff + f];
      for (int t = 0; t < Tt; ++t) {
        float xv = xp[(size_t)t * Ff];
#pragma unroll
        for (int i2 = 0; i2 < 6; ++i2) acc[i2] += ait_s[(r0 + i2) * Tt + t] * xv;
      }
#pragma unroll
      for (int i2 = 0; i2 < 6; ++i2) M_s[r0 + i2][f] = acc[i2];
    }
    __syncthreads();

    // ---- fc partials: 375 threads = (seg in [0,15): 2 r's) x (jq in [0,25))
    if (tid < 375) {
      const int seg = tid / 25, jq = tid % 25, r0 = seg * 2;
      float4 a = make_float4(0.f, 0.f, 0.f, 0.f);
#pragma unroll
      for (int ri = 0; ri < 2; ++ri) {
        const int r = r0 + ri;
        const float* wp = &Wfc[(size_t)(r * 100) * 100 + jq * 4];
#pragma unroll 4
        for (int f2 = 0; f2 < 100; ++f2) {
          const float mv = M_s[r][f2];
          const float4 wv = *(const float4*)&wp[(size_t)f2 * 100];
          a.x = fmaf(mv, wv.x, a.x); a.y = fmaf(mv, wv.y, a.y);
          a.z = fmaf(mv, wv.z, a.z); a.w = fmaf(mv, wv.w, a.w);
        }
      }
      *(float4*)&scratch[seg * 100 + jq * 4] = a;
    }
    __syncthreads();
    if (tid < 100) {
      float v = bfc[tid];
#pragma unroll
      for (int seg = 0; seg < 15; ++seg) v += scratch[seg * 100 + tid];
      fc_sm[tid] = fmaxf(v, 0.f);
    }
    __syncthreads();

    // ---- GRU gate partials: 300 threads = unit x (ks in [0,4)) x (jq in [0,25))
    if (tid < 300) {
      const int unit = tid / 100, rem = tid % 100, ks = rem / 25, jq = rem % 25;
      const float* Wm = (unit == 0) ? Wz : (unit == 1) ? Wr : Wh;
      float4 a = make_float4(0.f, 0.f, 0.f, 0.f);
      const float* wp = &Wm[ks * 25 * 100 + jq * 4];
#pragma unroll 5
      for (int k = 0; k < 25; ++k) {
        const float fv = fc_sm[ks * 25 + k];
        const float4 wv = *(const float4*)&wp[k * 100];
        a.x = fmaf(fv, wv.x, a.x); a.y = fmaf(fv, wv.y, a.y);
        a.z = fmaf(fv, wv.z, a.z); a.w = fmaf(fv, wv.w, a.w);
      }
      if (unit < 2) {
        const float* Um = (unit == 0) ? Uz : Ur;
        const float* up = &Um[ks * 25 * 100 + jq * 4];
#pragma unroll 5
        for (int k = 0; k < 25; ++k) {
          const float hv = h_sm[ks * 25 + k];
          const float4 uv = *(const float4*)&up[k * 100];
          a.x = fmaf(hv, uv.x, a.x); a.y = fmaf(hv, uv.y, a.y);
          a.z = fmaf(hv, uv.z, a.z); a.w = fmaf(hv, uv.w, a.w);
        }
      }
      *(float4*)&scratch[(unit * 4 + ks) * 100 + jq * 4] = a;
    }
    __syncthreads();
    if (tid < 300) {
      const int unit = tid / 100, j = tid % 100;
      const float* bm = (unit == 0) ? bz : (unit == 1) ? br : bh;
      float a = bm[j] + scratch[(unit * 4) * 100 + j] + scratch[(unit * 4 + 1) * 100 + j] +
                scratch[(unit * 4 + 2) * 100 + j] + scratch[(unit * 4 + 3) * 100 + j];
      if (unit == 0)      z_sm[j] = 1.0f / (1.0f + expf(-a));
      else if (unit == 1) r_sm[j] = 1.0f / (1.0f + expf(-a));
      else                hc1_sm[j] = a;
    }
    __syncthreads();
    if (tid < 100) rh_sm[tid] = r_sm[tid] * h_sm[tid];
    __syncthreads();

    // ---- hp partials: 100 threads = (ks in [0,4)) x (jq in [0,25))
    if (tid < 100) {
      const int ks = tid / 25, jq = tid % 25;
      float4 a = make_float4(0.f, 0.f, 0.f, 0.f);
      const float* up = &Uh[ks * 25 * 100 + jq * 4];
#pragma unroll 5
      for (int k = 0; k < 25; ++k) {
        const float rv = rh_sm[ks * 25 + k];
        const float4 uv = *(const float4*)&up[k * 100];
        a.x = fmaf(rv, uv.x, a.x); a.y = fmaf(rv, uv.y, a.y);
        a.z = fmaf(rv, uv.z, a.z); a.w = fmaf(rv, uv.w, a.w);
      }
      *(float4*)&scratch[ks * 100 + jq * 4] = a;
    }
    __syncthreads();
    if (tid < 100) {
      const int j = tid;
      float acc = hc1_sm[j] + scratch[j] + scratch[100 + j] + scratch[200 + j] + scratch[300 + j];
      float hp = tanhf(acc);
      float z = z_sm[j];
      float hn = (1.0f - z) * h_sm[j] + z * hp;
      out[((size_t)b * Ss + sg) * Hh + j] = hn;
      h_sm[j] = hn;  // only thread j reads h_sm[j] in this phase
    }
    __syncthreads();
  }

  if (tid < Hh) hstate[b * Hh + tid] = h_sm[tid];
}

// ---------------------------------------------------------------------------
extern "C" void kernel_launch(void* const* d_in, const int* in_sizes, int n_in,
                              void* d_out, int out_size, void* d_ws, size_t ws_size,
                              hipStream_t stream) {
  const float* x   = (const float*)d_in[0];
  const float* W   = (const float*)d_in[1];
  const float* Wc  = (const float*)d_in[2];
  const float* bv  = (const float*)d_in[3];
  const float* u   = (const float*)d_in[4];
  const float* Wfc = (const float*)d_in[5];
  const float* bfc = (const float*)d_in[6];
  const float* Wz  = (const float*)d_in[7];
  const float* Wr  = (const float*)d_in[8];
  const float* Wh  = (const float*)d_in[9];
  const float* Uz  = (const float*)d_in[10];
  const float* Ur  = (const float*)d_in[11];
  const float* Uh  = (const float*)d_in[12];
  const float* bz  = (const float*)d_in[13];
  const float* br  = (const float*)d_in[14];
  const float* bh  = (const float*)d_in[15];
  float* out = (float*)d_out;
  float* ws  = (float*)d_ws;

  int SC = 8;  // sentences per chunk; xw chunk = SC*2252800 floats (~72 MB @ 8)
  while (SC > 1 && ((size_t)WS_XW + (size_t)SC * 2252800) * 4 > ws_size) SC >>= 1;
  const int NC = Ss / SC;

  float* WT   = ws + WS_WT;
  float* upad = ws + WS_UPAD;
  float* WcT  = ws + WS_WCT;
  float* bpad = ws + WS_BPAD;
  float* hst  = ws + WS_HST;
  float* xw   = ws + WS_XW;

  k_prep<<<140, 256, 0, stream>>>(W, u, Wc, bv, ws);
  for (int c = 0; c < NC; ++c) {
    k_gemm<<<dim3(100 * SC, 3), 256, 0, stream>>>(x, WT, xw, c, SC);
    k_scan<<<128, 512, 0, stream>>>(x, xw, WcT, bpad, upad, Wfc, bfc,
                                    Wz, Wr, Wh, Uz, Ur, Uh, bz, br, bh,
                                    out, hst, c, SC);
  }
}